// Round 17
// baseline (1562.960 us; speedup 1.0000x reference)
//
#include <hip/hip_runtime.h>
#include <math.h>
#include <stdio.h>

#define Bv 4
#define Sv 2048
#define Dv 768
#define Hv 12
#define Lv 6
#define Fv 3072
#define Vv 512
#define Mv (Bv*Sv)   // 8192 rows

typedef __bf16 bf16;
typedef __bf16 bf16x8 __attribute__((ext_vector_type(8)));
typedef __bf16 bf16x4 __attribute__((ext_vector_type(4)));
typedef short  s16x4  __attribute__((ext_vector_type(4)));
typedef float  f32x4  __attribute__((ext_vector_type(4)));

// global -> LDS async copy, 16B per lane. LDS dest is wave-uniform base + lane*16.
__device__ __forceinline__ void gload_lds16(const void* g, void* l) {
  __builtin_amdgcn_global_load_lds(
      (__attribute__((address_space(1))) void*)(void*)g,
      (__attribute__((address_space(3))) void*)l, 16, 0, 0);
}

// bijective XCD-aware remap of a linear workgroup id (m204 formula)
__device__ __forceinline__ int xcd_remap(int orig, int nwg) {
  int q = nwg >> 3, r = nwg & 7;
  int xcd = orig & 7, loc = orig >> 3;
  return (xcd < r ? xcd * (q + 1) : r * (q + 1) + (xcd - r) * q) + loc;
}

// ---------------- token dtype probe: int64 -> all odd 32-bit words zero ----------------
__global__ void detect_i64(const int* __restrict__ x, int* __restrict__ flag) {
  __shared__ int red[256];
  int acc = 0;
  for (int i = threadIdx.x; i < Mv / 2; i += 256) acc |= x[2 * i + 1];
  red[threadIdx.x] = acc;
  __syncthreads();
  for (int s = 128; s > 0; s >>= 1) {
    if (threadIdx.x < s) red[threadIdx.x] |= red[threadIdx.x + s];
    __syncthreads();
  }
  if (threadIdx.x == 0) *flag = (red[0] == 0) ? 1 : 0;
}

// ---------------- embedding + sinusoidal positional encoding ----------------
__global__ void embed_kernel(const int* __restrict__ x, const float* __restrict__ emb,
                             float* __restrict__ h, const int* __restrict__ i64flag) {
  int idx = blockIdx.x * 256 + threadIdx.x;       // over Mv * (Dv/2)
  int j  = idx % (Dv / 2);
  int bs = idx / (Dv / 2);
  int s  = bs % Sv;
  int tok = (*i64flag) ? x[2 * bs] : x[bs];
  float2 e = *(const float2*)(emb + (size_t)tok * Dv + 2 * j);
  float div = expf((float)(2 * j) * (-9.210340371976184f / (float)Dv)); // -ln(10000)/D
  float arg = (float)s * div;
  const float sq = 27.712812921102035f;           // sqrt(768)
  float2 o;
  o.x = e.x * sq + sinf(arg);
  o.y = e.y * sq + cosf(arg);
  *(float2*)(h + (size_t)bs * Dv + 2 * j) = o;
}

// ---------------- fp32 [K,N] -> bf16 [N,K] tiled transpose-convert (z = layer) --------
__global__ void transpose_cvt(const float* __restrict__ in, bf16* __restrict__ out,
                              int K, int N) {
  __shared__ float tile[64][65];
  in  += (size_t)blockIdx.z * K * N;
  out += (size_t)blockIdx.z * K * N;
  int n0 = blockIdx.x * 64, k0 = blockIdx.y * 64;
  int tx = threadIdx.x & 63, ty = threadIdx.x >> 6;
#pragma unroll
  for (int i = 0; i < 64; i += 4)
    tile[ty + i][tx] = in[(size_t)(k0 + ty + i) * N + n0 + tx];
  __syncthreads();
#pragma unroll
  for (int i = 0; i < 64; i += 4)
    out[(size_t)(n0 + ty + i) * K + k0 + tx] = (bf16)tile[tx][ty + i];
}

// ---------------- LayerNorm: fp32 in -> bf16 out, one wave per row ----------------
__global__ void ln_kernel(const float* __restrict__ hin, const float* __restrict__ sc,
                          const float* __restrict__ bi, bf16* __restrict__ out) {
  int row  = blockIdx.x * 4 + (threadIdx.x >> 6);
  int lane = threadIdx.x & 63;
  const float* p = hin + (size_t)row * Dv + lane * 12;
  float v[12];
  *(float4*)(v)     = *(const float4*)(p);
  *(float4*)(v + 4) = *(const float4*)(p + 4);
  *(float4*)(v + 8) = *(const float4*)(p + 8);
  float sum = 0.f, sq = 0.f;
#pragma unroll
  for (int j = 0; j < 12; ++j) { sum += v[j]; sq += v[j] * v[j]; }
#pragma unroll
  for (int m = 1; m < 64; m <<= 1) {
    sum += __shfl_xor(sum, m, 64);
    sq  += __shfl_xor(sq,  m, 64);
  }
  float mu  = sum * (1.f / 768.f);
  float var = sq * (1.f / 768.f) - mu * mu;
  float rs  = rsqrtf(var + 1e-5f);
  float s_[12], b_[12];
  const float* scp = sc + lane * 12;
  const float* bip = bi + lane * 12;
  *(float4*)(s_)     = *(const float4*)(scp);
  *(float4*)(s_ + 4) = *(const float4*)(scp + 4);
  *(float4*)(s_ + 8) = *(const float4*)(scp + 8);
  *(float4*)(b_)     = *(const float4*)(bip);
  *(float4*)(b_ + 4) = *(const float4*)(bip + 4);
  *(float4*)(b_ + 8) = *(const float4*)(bip + 8);
  union { bf16 h2[12]; uint2 q[3]; } ob;
#pragma unroll
  for (int j = 0; j < 12; ++j)
    ob.h2[j] = (bf16)((v[j] - mu) * rs * s_[j] + b_[j]);
  uint2* op = (uint2*)(out + (size_t)row * Dv + lane * 12);
  op[0] = ob.q[0]; op[1] = ob.q[1]; op[2] = ob.q[2];
}

// ---------------- 128x128 bf16 GEMM, counted-vmcnt double-buffered staging ----------
// OUTMODE: 0 = none (resid only), 1 = bf16 out, 2 = f32 out,
//          3 = QKV fused: bn<1536 -> bf16 out (Q,K); bn>=1536 -> V transposed
//              to vt[b,h,d,s] via padded-LDS transpose (coalesced 16B stores).
template<bool RELU, bool RESID, int OUTMODE>
__global__ __launch_bounds__(256) void gemm_bt(
    const bf16* __restrict__ A, const bf16* __restrict__ Bt,
    const float* __restrict__ bias, float* __restrict__ hres,
    bf16* __restrict__ outb, float* __restrict__ outf, bf16* __restrict__ vt,
    int M, int N, int K) {
  __shared__ bf16 smem[4][128 * 64];          // [0..1]=A dbuf, [2..3]=B dbuf
  const int gx = gridDim.x;
  const int wg = xcd_remap(blockIdx.y * gx + blockIdx.x, gx * gridDim.y);
  const int bn = (wg % gx) * 128, bm = (wg / gx) * 128;
  const int t = threadIdx.x, lane = t & 63, wid = t >> 6;
  const int wr = wid >> 1, wc = wid & 1;
  const int g = lane >> 4, c = lane & 15;
  f32x4 acc[4][4];
#pragma unroll
  for (int i = 0; i < 4; ++i)
#pragma unroll
    for (int j = 0; j < 4; ++j) acc[i][j] = (f32x4){0.f, 0.f, 0.f, 0.f};
  const int nkt = K >> 6;

  auto stage = [&](int bb, int kt) {
#pragma unroll
    for (int j2 = 0; j2 < 4; ++j2) {
      int ch  = t + j2 * 256;                 // 0..1023 chunk (16B) index
      int row = ch >> 3;                      // 0..127
      int src = ((ch & 7) * 8) ^ ((row & 7) << 3);   // pre-swizzled source col
      gload_lds16(A  + (size_t)(bm + row) * K + kt * 64 + src, &smem[bb][ch * 8]);
      gload_lds16(Bt + (size_t)(bn + row) * K + kt * 64 + src, &smem[2 + bb][ch * 8]);
    }
  };

  stage(0, 0);
  const int swz = (c & 7) << 3;
  for (int kt = 0; kt < nkt; ++kt) {
    const int cb = kt & 1;
    if (kt + 1 < nkt) {
      stage(cb ^ 1, kt + 1);                  // prefetch flies under compute
      asm volatile("s_waitcnt vmcnt(8)" ::: "memory");   // wait current tile only
    } else {
      asm volatile("s_waitcnt vmcnt(0)" ::: "memory");
    }
    __builtin_amdgcn_s_barrier();
    __builtin_amdgcn_sched_barrier(0);
#pragma unroll
    for (int f = 0; f < 2; ++f) {
      bf16x8 aF[4], bF[4];
      const int e = (f * 32 + g * 8) ^ swz;
#pragma unroll
      for (int mt = 0; mt < 4; ++mt)
        aF[mt] = *(const bf16x8*)&smem[cb][(wr * 64 + mt * 16 + c) * 64 + e];
#pragma unroll
      for (int nt = 0; nt < 4; ++nt)
        bF[nt] = *(const bf16x8*)&smem[2 + cb][(wc * 64 + nt * 16 + c) * 64 + e];
      __builtin_amdgcn_s_setprio(1);
#pragma unroll
      for (int mt = 0; mt < 4; ++mt)
#pragma unroll
        for (int nt = 0; nt < 4; ++nt)
          acc[mt][nt] = __builtin_amdgcn_mfma_f32_16x16x32_bf16(
              aF[mt], bF[nt], acc[mt][nt], 0, 0, 0);
      __builtin_amdgcn_s_setprio(0);
    }
    __builtin_amdgcn_sched_barrier(0);
    __builtin_amdgcn_s_barrier();             // all done reading buf[cb]
  }
  // ---- epilogue: C/D layout col=lane&15, row=(lane>>4)*4+reg ----
  if (OUTMODE == 3 && bn >= 1536) {
    // V block: transpose C-tile via padded LDS, store coalesced to vt[b,h,d,s].
    bf16* ldsT = (bf16*)smem;                 // 128 x 136 bf16 = 34 KB (LDS free)
#pragma unroll
    for (int nt = 0; nt < 4; ++nt) {
      int lc = wc * 64 + nt * 16 + c;         // local col (= local d)
      float bv = bias[bn + lc];
#pragma unroll
      for (int mt = 0; mt < 4; ++mt) {
        int lr = wr * 64 + mt * 16 + g * 4;   // local row (= local s)
        bf16x4 pb;
#pragma unroll
        for (int r = 0; r < 4; ++r) pb[r] = (bf16)(acc[mt][nt][r] + bv);
        *(s16x4*)&ldsT[lc * 136 + lr] = __builtin_bit_cast(s16x4, pb);
      }
    }
    __syncthreads();
    const int vc0 = bn - 1536;                // global v-col base (0..640)
    const int bb_ = bm >> 11;                 // batch
    const int s0  = bm & 2047;                // s base
#pragma unroll
    for (int it = 0; it < 8; ++it) {
      int chunk = t + it * 256;               // 0..2047
      int d = chunk >> 4, sc = chunk & 15;
      bf16x8 v = *(const bf16x8*)&ldsT[d * 136 + sc * 8];
      int vcol = vc0 + d;
      size_t vrow = ((size_t)(bb_ * Hv + (vcol >> 6)) * 64 + (vcol & 63));
      *(bf16x8*)&vt[vrow * Sv + s0 + sc * 8] = v;
    }
    return;
  }
#pragma unroll
  for (int nt = 0; nt < 4; ++nt) {
    int col = bn + wc * 64 + nt * 16 + c;
    float bv = bias[col];
#pragma unroll
    for (int mt = 0; mt < 4; ++mt) {
      int row0 = bm + wr * 64 + mt * 16 + g * 4;
#pragma unroll
      for (int r = 0; r < 4; ++r) {
        float vv = acc[mt][nt][r] + bv;
        if (RELU) vv = fmaxf(vv, 0.f);
        size_t off = (size_t)(row0 + r) * N + col;
        if (RESID) { vv += hres[off]; hres[off] = vv; }
        if (OUTMODE == 1 || OUTMODE == 3) outb[off] = (bf16)vv;
        if (OUTMODE == 2) outf[off] = vv;
      }
    }
  }
}

// ---------------- 128x128 bf16 GEMM, SINGLE-buffered (m97 structure) ----------------
// 32 KB LDS -> 5 blocks/CU = 20 waves/CU: trades explicit prefetch for wave-level
// implicit overlap (m114). For FFN1 (grid 1536 blocks = 6/CU available).
template<bool RELU, bool RESID, int OUTMODE>
__global__ __launch_bounds__(256) void gemm_sb(
    const bf16* __restrict__ A, const bf16* __restrict__ Bt,
    const float* __restrict__ bias, float* __restrict__ hres,
    bf16* __restrict__ outb, float* __restrict__ outf, int M, int N, int K) {
  __shared__ bf16 sA[128 * 64];
  __shared__ bf16 sB[128 * 64];
  const int gx = gridDim.x;
  const int wg = xcd_remap(blockIdx.y * gx + blockIdx.x, gx * gridDim.y);
  const int bn = (wg % gx) * 128, bm = (wg / gx) * 128;
  const int t = threadIdx.x, lane = t & 63, wid = t >> 6;
  const int wr = wid >> 1, wc = wid & 1;
  const int g = lane >> 4, c = lane & 15;
  f32x4 acc[4][4];
#pragma unroll
  for (int i = 0; i < 4; ++i)
#pragma unroll
    for (int j = 0; j < 4; ++j) acc[i][j] = (f32x4){0.f, 0.f, 0.f, 0.f};
  const int nkt = K >> 6;
  const int swz = (c & 7) << 3;
  for (int kt = 0; kt < nkt; ++kt) {
    __syncthreads();                          // all waves done reading prev tile
#pragma unroll
    for (int j2 = 0; j2 < 4; ++j2) {
      int ch  = t + j2 * 256;                 // 0..1023 chunk (16B) index
      int row = ch >> 3;                      // 0..127
      int src = ((ch & 7) * 8) ^ ((row & 7) << 3);
      gload_lds16(A  + (size_t)(bm + row) * K + kt * 64 + src, &sA[ch * 8]);
      gload_lds16(Bt + (size_t)(bn + row) * K + kt * 64 + src, &sB[ch * 8]);
    }
    asm volatile("s_waitcnt vmcnt(0)" ::: "memory");
    __builtin_amdgcn_s_barrier();
#pragma unroll
    for (int f = 0; f < 2; ++f) {
      bf16x8 aF[4], bF[4];
      const int e = (f * 32 + g * 8) ^ swz;
#pragma unroll
      for (int mt = 0; mt < 4; ++mt)
        aF[mt] = *(const bf16x8*)&sA[(wr * 64 + mt * 16 + c) * 64 + e];
#pragma unroll
      for (int nt = 0; nt < 4; ++nt)
        bF[nt] = *(const bf16x8*)&sB[(wc * 64 + nt * 16 + c) * 64 + e];
      __builtin_amdgcn_s_setprio(1);
#pragma unroll
      for (int mt = 0; mt < 4; ++mt)
#pragma unroll
        for (int nt = 0; nt < 4; ++nt)
          acc[mt][nt] = __builtin_amdgcn_mfma_f32_16x16x32_bf16(
              aF[mt], bF[nt], acc[mt][nt], 0, 0, 0);
      __builtin_amdgcn_s_setprio(0);
    }
  }
  // epilogue
#pragma unroll
  for (int nt = 0; nt < 4; ++nt) {
    int col = bn + wc * 64 + nt * 16 + c;
    float bv = bias[col];
#pragma unroll
    for (int mt = 0; mt < 4; ++mt) {
      int row0 = bm + wr * 64 + mt * 16 + g * 4;
#pragma unroll
      for (int r = 0; r < 4; ++r) {
        float vv = acc[mt][nt][r] + bv;
        if (RELU) vv = fmaxf(vv, 0.f);
        size_t off = (size_t)(row0 + r) * N + col;
        if (RESID) { vv += hres[off]; hres[off] = vv; }
        if (OUTMODE == 1) outb[off] = (bf16)vv;
        if (OUTMODE == 2) outf[off] = vv;
      }
    }
  }
}

// ---------------- 64x128 bf16 GEMM (skinny-N), dbuf, 48KB LDS -> 3 blocks/CU --------
template<bool RELU, bool RESID, int OUTMODE>
__global__ __launch_bounds__(256) void gemm_sk(
    const bf16* __restrict__ A, const bf16* __restrict__ Bt,
    const float* __restrict__ bias, float* __restrict__ hres,
    bf16* __restrict__ outb, float* __restrict__ outf, int M, int N, int K) {
  __shared__ bf16 sA[2][64 * 64];
  __shared__ bf16 sB[2][128 * 64];
  const int gx = gridDim.x;
  const int wg = xcd_remap(blockIdx.y * gx + blockIdx.x, gx * gridDim.y);
  const int bn = (wg % gx) * 128, bm = (wg / gx) * 64;
  const int t = threadIdx.x, lane = t & 63, wid = t >> 6;
  const int wr = wid >> 1, wc = wid & 1;      // 2M x 2N of 32x64 per wave
  const int g = lane >> 4, c = lane & 15;
  f32x4 acc[2][4];
#pragma unroll
  for (int i = 0; i < 2; ++i)
#pragma unroll
    for (int j = 0; j < 4; ++j) acc[i][j] = (f32x4){0.f, 0.f, 0.f, 0.f};
  const int nkt = K >> 6;

  auto stage = [&](int bb, int kt) {
#pragma unroll
    for (int j2 = 0; j2 < 2; ++j2) {          // A: 64x64 = 512 chunks
      int ch  = t + j2 * 256;
      int row = ch >> 3;                      // 0..63
      int src = ((ch & 7) * 8) ^ ((row & 7) << 3);
      gload_lds16(A + (size_t)(bm + row) * K + kt * 64 + src, &sA[bb][ch * 8]);
    }
#pragma unroll
    for (int j2 = 0; j2 < 4; ++j2) {          // B: 128x64 = 1024 chunks
      int ch  = t + j2 * 256;
      int row = ch >> 3;                      // 0..127
      int src = ((ch & 7) * 8) ^ ((row & 7) << 3);
      gload_lds16(Bt + (size_t)(bn + row) * K + kt * 64 + src, &sB[bb][ch * 8]);
    }
  };

  stage(0, 0);
  const int swz = (c & 7) << 3;
  for (int kt = 0; kt < nkt; ++kt) {
    const int cb = kt & 1;
    if (kt + 1 < nkt) {
      stage(cb ^ 1, kt + 1);
      asm volatile("s_waitcnt vmcnt(6)" ::: "memory");   // 6 loads/thread/stage
    } else {
      asm volatile("s_waitcnt vmcnt(0)" ::: "memory");
    }
    __builtin_amdgcn_s_barrier();
    __builtin_amdgcn_sched_barrier(0);
#pragma unroll
    for (int f = 0; f < 2; ++f) {
      bf16x8 aF[2], bF[4];
      const int e = (f * 32 + g * 8) ^ swz;
#pragma unroll
      for (int mt = 0; mt < 2; ++mt)
        aF[mt] = *(const bf16x8*)&sA[cb][(wr * 32 + mt * 16 + c) * 64 + e];
#pragma unroll
      for (int nt = 0; nt < 4; ++nt)
        bF[nt] = *(const bf16x8*)&sB[cb][(wc * 64 + nt * 16 + c) * 64 + e];
      __builtin_amdgcn_s_setprio(1);
#pragma unroll
      for (int mt = 0; mt < 2; ++mt)
#pragma unroll
        for (int nt = 0; nt < 4; ++nt)
          acc[mt][nt] = __builtin_amdgcn_mfma_f32_16x16x32_bf16(
              aF[mt], bF[nt], acc[mt][nt], 0, 0, 0);
      __builtin_amdgcn_s_setprio(0);
    }
    __builtin_amdgcn_sched_barrier(0);
    __builtin_amdgcn_s_barrier();
  }
  // epilogue
#pragma unroll
  for (int nt = 0; nt < 4; ++nt) {
    int col = bn + wc * 64 + nt * 16 + c;
    float bv = bias[col];
#pragma unroll
    for (int mt = 0; mt < 2; ++mt) {
      int row0 = bm + wr * 32 + mt * 16 + g * 4;
#pragma unroll
      for (int r = 0; r < 4; ++r) {
        float vv = acc[mt][nt][r] + bv;
        if (RELU) vv = fmaxf(vv, 0.f);
        size_t off = (size_t)(row0 + r) * N + col;
        if (RESID) { vv += hres[off]; hres[off] = vv; }
        if (OUTMODE == 1) outb[off] = (bf16)vv;
        if (OUTMODE == 2) outf[off] = vv;
      }
    }
  }
}

// ---------------- flash attention (swapped-QK^T, zero-shuffle PV, paired) ----------
// l-sum via ones-MFMA; max3-fused reduction.
__global__ __launch_bounds__(256) void attn_kernel(const bf16* __restrict__ qkv,
                                                   const bf16* __restrict__ vt,
                                                   bf16* __restrict__ o) {
  __shared__ bf16 sK[2][64 * 64], sVT[2][64 * 64];
  const int nwg = 16 * Bv * Hv;
  const int wgl = xcd_remap(blockIdx.y * 16 + blockIdx.x, nwg);
  const int i  = wgl % 16;                    // pair index 0..15
  const int bh = wgl / 16;
  const int qtA = i, qtB = 31 - i;
  const int b  = bh / Hv;
  const int h  = bh % Hv;
  const int t = threadIdx.x, lane = t & 63, wid = t >> 6;
  const int g = lane >> 4, c = lane & 15;
  const int QST = 2304;
  const bf16* qbase  = qkv + (size_t)b * Sv * QST + h * 64;
  const bf16* vtbase = vt + ((size_t)bh * 64) * Sv;
  const float CS = 0.18033688011112042f;      // (1/sqrt(64)) * log2(e)
  const float THR = 11.541560327111707f;      // 8 * log2(e) (defer-max)
  const int swz = (c & 7) << 3;
  const s16x4 onesf = {0x3F80, 0x3F80, 0x3F80, 0x3F80};   // bf16 1.0 x4

  bf16x8 qfA[2], qfB[2];
  {
    const bf16* qa = qbase + (size_t)(qtA * 64 + wid * 16 + c) * QST;
    qfA[0] = *(const bf16x8*)(qa + g * 8);
    qfA[1] = *(const bf16x8*)(qa + 32 + g * 8);
    const bf16* qb = qbase + (size_t)(qtB * 64 + wid * 16 + c) * QST;
    qfB[0] = *(const bf16x8*)(qb + g * 8);
    qfB[1] = *(const bf16x8*)(qb + 32 + g * 8);
  }
  f32x4 accA[4], accB[4];
  f32x4 accLA = {0.f, 0.f, 0.f, 0.f}, accLB = {0.f, 0.f, 0.f, 0.f};
  float mA = -INFINITY, mB = -INFINITY;
#pragma unroll
  for (int d0 = 0; d0 < 4; ++d0) {
    accA[d0] = (f32x4){0.f, 0.f, 0.f, 0.f};
    accB[d0] = (f32x4){0.f, 0.f, 0.f, 0.f};
  }
  const int qlA = qtA * 64 + wid * 16 + c;    // this lane's softmax query (A)
  const int qlB = qtB * 64 + wid * 16 + c;

  auto stage = [&](int bb, int kt) {
#pragma unroll
    for (int j2 = 0; j2 < 2; ++j2) {
      int ch  = t + j2 * 256;                 // 0..511
      int row = ch >> 3;                      // 0..63
      int src = ((ch & 7) * 8) ^ ((row & 7) << 3);
      gload_lds16(qbase + (size_t)(kt * 64 + row) * QST + 768 + src, &sK[bb][ch * 8]);
      gload_lds16(vtbase + (size_t)row * Sv + kt * 64 + src, &sVT[bb][ch * 8]);
    }
  };

  auto process = [&](int bb, const bf16x8* qf, f32x4* accO, f32x4& accL,
                     float& m_s, int ql, int kt, bool diag) {
    f32x4 accT[4];
#pragma unroll
    for (int nt = 0; nt < 4; ++nt) accT[nt] = (f32x4){0.f, 0.f, 0.f, 0.f};
    __builtin_amdgcn_s_setprio(1);
#pragma unroll
    for (int nt = 0; nt < 4; ++nt)
#pragma unroll
      for (int f = 0; f < 2; ++f) {
        bf16x8 kf = *(const bf16x8*)&sK[bb][(nt * 16 + c) * 64 + ((f * 32 + g * 8) ^ swz)];
        accT[nt] = __builtin_amdgcn_mfma_f32_16x16x32_bf16(kf, qf[f], accT[nt], 0, 0, 0);
      }
    __builtin_amdgcn_s_setprio(0);
    if (diag) {                               // wave-uniform branch; raw-score mask
#pragma unroll
      for (int nt = 0; nt < 4; ++nt)
#pragma unroll
        for (int r = 0; r < 4; ++r)
          if ((kt * 64 + nt * 16 + g * 4 + r) > ql) accT[nt][r] = -INFINITY;
    }
    // max3-fused reduction (clang folds fmaxf(fmaxf(a,b),c) -> v_max3_f32)
    float mnt[4];
#pragma unroll
    for (int nt = 0; nt < 4; ++nt)
      mnt[nt] = fmaxf(fmaxf(fmaxf(accT[nt][0], accT[nt][1]), accT[nt][2]),
                      accT[nt][3]);
    float mt = fmaxf(fmaxf(fmaxf(mnt[0], mnt[1]), mnt[2]), mnt[3]);
    mt *= CS;
    mt = fmaxf(mt, __shfl_xor(mt, 16, 64));
    mt = fmaxf(mt, __shfl_xor(mt, 32, 64));
    const bool skip = __all(mt <= m_s + THR);   // defer-max (wave-uniform)
    const float mn = skip ? m_s : fmaxf(m_s, mt);
    if (!skip) {
      float al = __builtin_amdgcn_exp2f(m_s - mn);
      m_s = mn;
#pragma unroll
      for (int r = 0; r < 4; ++r) {
        float alq = __shfl(al, g * 4 + r, 64); // al of query g*4+r (lanes 0..15)
        accL[r] *= alq;
#pragma unroll
        for (int d0 = 0; d0 < 4; ++d0) accO[d0][r] *= alq;
      }
    }
#pragma unroll
    for (int nt = 0; nt < 4; ++nt)
#pragma unroll
      for (int r = 0; r < 4; ++r)
        accT[nt][r] = __builtin_amdgcn_exp2f(fmaf(accT[nt][r], CS, -mn));
    // PV from registers: pa[nt] = A-frag (row=query c, k=g*4+e) of K=16 slice nt
    s16x4 pa[4];
#pragma unroll
    for (int nt = 0; nt < 4; ++nt) {
      bf16x4 pb;
#pragma unroll
      for (int r = 0; r < 4; ++r) pb[r] = (bf16)accT[nt][r];
      pa[nt] = __builtin_bit_cast(s16x4, pb);
    }
    __builtin_amdgcn_s_setprio(1);
#pragma unroll
    for (int nt = 0; nt < 4; ++nt)            // denominator: accL += P . ones
      accL = __builtin_amdgcn_mfma_f32_16x16x16bf16_1k(pa[nt], onesf, accL, 0, 0, 0);
#pragma unroll
    for (int d0 = 0; d0 < 4; ++d0) {
      const int drow = (d0 * 16 + c) * 64;
#pragma unroll
      for (int nt = 0; nt < 4; ++nt) {
        int chunk = (nt * 2 + (g >> 1)) ^ (c & 7);
        s16x4 vfr = *(const s16x4*)&sVT[bb][drow + chunk * 8 + (g & 1) * 4];
        accO[d0] = __builtin_amdgcn_mfma_f32_16x16x16bf16_1k(pa[nt], vfr, accO[d0], 0, 0, 0);
      }
    }
    __builtin_amdgcn_s_setprio(0);
  };

  stage(0, 0);
  int cur = 0;
  for (int kt = 0; kt <= qtB; ++kt) {
    __syncthreads();                          // publishes buf[cur] (vmcnt drain)
    if (kt < qtB) stage(cur ^ 1, kt + 1);     // prefetch flies under compute
    if (kt <= qtA) process(cur, qfA, accA, accLA, mA, qlA, kt, kt == qtA);
    process(cur, qfB, accB, accLB, mB, qlB, kt, kt == qtB);
    cur ^= 1;
  }

  // normalize + store; accO/accL row r = query g*4+r (no shuffles needed)
#pragma unroll
  for (int r = 0; r < 4; ++r) {
    float iA = 1.f / accLA[r];
    float iB = 1.f / accLB[r];
    size_t orA = (size_t)b * Sv + qtA * 64 + wid * 16 + g * 4 + r;
    size_t orB = (size_t)b * Sv + qtB * 64 + wid * 16 + g * 4 + r;
#pragma unroll
    for (int d0 = 0; d0 < 4; ++d0) {
      o[orA * Dv + h * 64 + d0 * 16 + c] = (bf16)(accA[d0][r] * iA);
      o[orB * Dv + h * 64 + d0 * 16 + c] = (bf16)(accB[d0][r] * iB);
    }
  }
}

// ---------------- host launch ----------------
extern "C" void kernel_launch(void* const* d_in, const int* in_sizes, int n_in,
                              void* d_out, int out_size, void* d_ws, size_t ws_size,
                              hipStream_t stream) {
  const int*   x     = (const int*)d_in[0];
  const float* emb   = (const float*)d_in[1];
  const float* qkv_w = (const float*)d_in[2];
  const float* qkv_b = (const float*)d_in[3];
  const float* out_w = (const float*)d_in[4];
  const float* out_b = (const float*)d_in[5];
  const float* ln1_s = (const float*)d_in[6];
  const float* ln1_b = (const float*)d_in[7];
  const float* w1    = (const float*)d_in[8];
  const float* b1    = (const float*)d_in[9];
  const float* w2    = (const float*)d_in[10];
  const float* b2    = (const float*)d_in[11];
  const float* ln2_s = (const float*)d_in[12];
  const float* ln2_b = (const float*)d_in[13];
  const float* lnf_s = (const float*)d_in[14];
  const float* lnf_b = (const float*)d_in[15];
  const float* head_w= (const float*)d_in[16];
  const float* head_b= (const float*)d_in[17];
  float* out = (float*)d_out;                 // reference output dtype = float32
  (void)in_sizes; (void)n_in; (void)out_size;

  char* ws = (char*)d_ws;
  size_t off = 0;
  auto alloc = [&](size_t bytes) -> char* {
    char* p = ws + off; off += (bytes + 255) & ~(size_t)255; return p;
  };
  float* hbuf  = (float*)alloc((size_t)Mv * Dv * 4);        // fp32 residual stream
  bf16*  xn    = (bf16*) alloc((size_t)Mv * Dv * 2);        // LN output
  bf16*  qkvff = (bf16*) alloc((size_t)Mv * Fv * 2);        // qkv (M*2304) / ff (M*3072)
  bf16*  vt    = (bf16*) alloc((size_t)Bv * Hv * 64 * Sv * 2); // V^T [b,h,d,s]
  bf16*  attn_o= (bf16*) alloc((size_t)Mv * Dv * 2);
  bf16*  qkvT  = (bf16*) alloc((size_t)Lv * 3 * Dv * Dv * 2); // all-layer transposed W
  bf16*  outT  = (bf16*) alloc((size_t)Lv * Dv * Dv * 2);
  bf16*  w1T   = (bf16*) alloc((size_t)Lv * Fv * Dv * 2);
  bf16*  w2T   = (bf16*) alloc((size_t)Lv * Fv * Dv * 2);
  bf16*  headT = (bf16*) alloc((size_t)Vv * Dv * 2);
  int*   i64f  = (int*)  alloc(256);

  fprintf(stderr, "[kernel_launch] ws_size=%zu needed=%zu out_size=%d\n",
          ws_size, off, out_size);
  if (off > ws_size) {
    fprintf(stderr, "[kernel_launch] WORKSPACE TOO SMALL - not launching\n");
    return;
  }

  detect_i64<<<1, 256, 0, stream>>>(x, i64f);
  transpose_cvt<<<dim3(36, 12, Lv), 256, 0, stream>>>(qkv_w, qkvT, Dv, 3 * Dv);
  transpose_cvt<<<dim3(12, 12, Lv), 256, 0, stream>>>(out_w, outT, Dv, Dv);
  transpose_cvt<<<dim3(48, 12, Lv), 256, 0, stream>>>(w1, w1T, Dv, Fv);
  transpose_cvt<<<dim3(12, 48, Lv), 256, 0, stream>>>(w2, w2T, Fv, Dv);
  transpose_cvt<<<dim3(8, 12, 1), 256, 0, stream>>>(head_w, headT, Dv, Vv);
  embed_kernel<<<Mv * (Dv / 2) / 256, 256, 0, stream>>>(x, emb, hbuf, i64f);

  for (int l = 0; l < Lv; ++l) {
    ln_kernel<<<Mv / 4, 256, 0, stream>>>(hbuf, ln1_s + l * Dv, ln1_b + l * Dv, xn);
    gemm_bt<false, false, 3><<<dim3(3 * Dv / 128, Mv / 128), 256, 0, stream>>>(
        xn, qkvT + (size_t)l * 3 * Dv * Dv, qkv_b + l * 3 * Dv, nullptr, qkvff,
        nullptr, vt, Mv, 3 * Dv, Dv);
    attn_kernel<<<dim3(16, Bv * Hv), 256, 0, stream>>>(qkvff, vt, attn_o);
    gemm_sk<false, true, 0><<<dim3(Dv / 128, Mv / 64), 256, 0, stream>>>(
        attn_o, outT + (size_t)l * Dv * Dv, out_b + l * Dv, hbuf, nullptr,
        nullptr, Mv, Dv, Dv);
    ln_kernel<<<Mv / 4, 256, 0, stream>>>(hbuf, ln2_s + l * Dv, ln2_b + l * Dv, xn);
    gemm_sb<true, false, 1><<<dim3(Fv / 128, Mv / 128), 256, 0, stream>>>(
        xn, w1T + (size_t)l * Fv * Dv, b1 + l * Fv, nullptr, qkvff, nullptr,
        Mv, Fv, Dv);
    gemm_sk<false, true, 0><<<dim3(Dv / 128, Mv / 64), 256, 0, stream>>>(
        qkvff, w2T + (size_t)l * Fv * Dv, b2 + l * Dv, hbuf, nullptr, nullptr,
        Mv, Dv, Fv);
  }
  ln_kernel<<<Mv / 4, 256, 0, stream>>>(hbuf, lnf_s, lnf_b, xn);
  gemm_sk<false, false, 2><<<dim3(Vv / 128, Mv / 64), 256, 0, stream>>>(
      xn, headT, head_b, nullptr, nullptr, out, Mv, Vv, Dv);
}

// Round 18
// 1550.940 us; speedup vs baseline: 1.0077x; 1.0077x over previous
//
#include <hip/hip_runtime.h>
#include <math.h>
#include <stdio.h>

#define Bv 4
#define Sv 2048
#define Dv 768
#define Hv 12
#define Lv 6
#define Fv 3072
#define Vv 512
#define Mv (Bv*Sv)   // 8192 rows

typedef __bf16 bf16;
typedef __bf16 bf16x8 __attribute__((ext_vector_type(8)));
typedef __bf16 bf16x4 __attribute__((ext_vector_type(4)));
typedef short  s16x4  __attribute__((ext_vector_type(4)));
typedef float  f32x4  __attribute__((ext_vector_type(4)));

// global -> LDS async copy, 16B per lane. LDS dest is wave-uniform base + lane*16.
__device__ __forceinline__ void gload_lds16(const void* g, void* l) {
  __builtin_amdgcn_global_load_lds(
      (__attribute__((address_space(1))) void*)(void*)g,
      (__attribute__((address_space(3))) void*)l, 16, 0, 0);
}

// bijective XCD-aware remap of a linear workgroup id (m204 formula)
__device__ __forceinline__ int xcd_remap(int orig, int nwg) {
  int q = nwg >> 3, r = nwg & 7;
  int xcd = orig & 7, loc = orig >> 3;
  return (xcd < r ? xcd * (q + 1) : r * (q + 1) + (xcd - r) * q) + loc;
}

// ---------------- token dtype probe: int64 -> all odd 32-bit words zero ----------------
__global__ void detect_i64(const int* __restrict__ x, int* __restrict__ flag) {
  __shared__ int red[256];
  int acc = 0;
  for (int i = threadIdx.x; i < Mv / 2; i += 256) acc |= x[2 * i + 1];
  red[threadIdx.x] = acc;
  __syncthreads();
  for (int s = 128; s > 0; s >>= 1) {
    if (threadIdx.x < s) red[threadIdx.x] |= red[threadIdx.x + s];
    __syncthreads();
  }
  if (threadIdx.x == 0) *flag = (red[0] == 0) ? 1 : 0;
}

// ---------------- embedding + sinusoidal positional encoding ----------------
__global__ void embed_kernel(const int* __restrict__ x, const float* __restrict__ emb,
                             float* __restrict__ h, const int* __restrict__ i64flag) {
  int idx = blockIdx.x * 256 + threadIdx.x;       // over Mv * (Dv/2)
  int j  = idx % (Dv / 2);
  int bs = idx / (Dv / 2);
  int s  = bs % Sv;
  int tok = (*i64flag) ? x[2 * bs] : x[bs];
  float2 e = *(const float2*)(emb + (size_t)tok * Dv + 2 * j);
  float div = expf((float)(2 * j) * (-9.210340371976184f / (float)Dv)); // -ln(10000)/D
  float arg = (float)s * div;
  const float sq = 27.712812921102035f;           // sqrt(768)
  float2 o;
  o.x = e.x * sq + sinf(arg);
  o.y = e.y * sq + cosf(arg);
  *(float2*)(h + (size_t)bs * Dv + 2 * j) = o;
}

// ---------------- fp32 [K,N] -> bf16 [N,K] tiled transpose-convert (z = layer) --------
__global__ void transpose_cvt(const float* __restrict__ in, bf16* __restrict__ out,
                              int K, int N) {
  __shared__ float tile[64][65];
  in  += (size_t)blockIdx.z * K * N;
  out += (size_t)blockIdx.z * K * N;
  int n0 = blockIdx.x * 64, k0 = blockIdx.y * 64;
  int tx = threadIdx.x & 63, ty = threadIdx.x >> 6;
#pragma unroll
  for (int i = 0; i < 64; i += 4)
    tile[ty + i][tx] = in[(size_t)(k0 + ty + i) * N + n0 + tx];
  __syncthreads();
#pragma unroll
  for (int i = 0; i < 64; i += 4)
    out[(size_t)(n0 + ty + i) * K + k0 + tx] = (bf16)tile[tx][ty + i];
}

// ---------------- LayerNorm: fp32 in -> bf16 out, one wave per row ----------------
__global__ void ln_kernel(const float* __restrict__ hin, const float* __restrict__ sc,
                          const float* __restrict__ bi, bf16* __restrict__ out) {
  int row  = blockIdx.x * 4 + (threadIdx.x >> 6);
  int lane = threadIdx.x & 63;
  const float* p = hin + (size_t)row * Dv + lane * 12;
  float v[12];
  *(float4*)(v)     = *(const float4*)(p);
  *(float4*)(v + 4) = *(const float4*)(p + 4);
  *(float4*)(v + 8) = *(const float4*)(p + 8);
  float sum = 0.f, sq = 0.f;
#pragma unroll
  for (int j = 0; j < 12; ++j) { sum += v[j]; sq += v[j] * v[j]; }
#pragma unroll
  for (int m = 1; m < 64; m <<= 1) {
    sum += __shfl_xor(sum, m, 64);
    sq  += __shfl_xor(sq,  m, 64);
  }
  float mu  = sum * (1.f / 768.f);
  float var = sq * (1.f / 768.f) - mu * mu;
  float rs  = rsqrtf(var + 1e-5f);
  float s_[12], b_[12];
  const float* scp = sc + lane * 12;
  const float* bip = bi + lane * 12;
  *(float4*)(s_)     = *(const float4*)(scp);
  *(float4*)(s_ + 4) = *(const float4*)(scp + 4);
  *(float4*)(s_ + 8) = *(const float4*)(scp + 8);
  *(float4*)(b_)     = *(const float4*)(bip);
  *(float4*)(b_ + 4) = *(const float4*)(bip + 4);
  *(float4*)(b_ + 8) = *(const float4*)(bip + 8);
  union { bf16 h2[12]; uint2 q[3]; } ob;
#pragma unroll
  for (int j = 0; j < 12; ++j)
    ob.h2[j] = (bf16)((v[j] - mu) * rs * s_[j] + b_[j]);
  uint2* op = (uint2*)(out + (size_t)row * Dv + lane * 12);
  op[0] = ob.q[0]; op[1] = ob.q[1]; op[2] = ob.q[2];
}

// ---------------- 128x128 bf16 GEMM, counted-vmcnt double-buffered staging ----------
// OUTMODE: 0 = none (resid only), 1 = bf16 out, 2 = f32 out,
//          3 = QKV fused: bn<1536 -> bf16 out (Q,K); bn>=1536 -> V transposed
//              to vt[b,h,d,s] via padded-LDS transpose (coalesced 16B stores).
template<bool RELU, bool RESID, int OUTMODE>
__global__ __launch_bounds__(256) void gemm_bt(
    const bf16* __restrict__ A, const bf16* __restrict__ Bt,
    const float* __restrict__ bias, float* __restrict__ hres,
    bf16* __restrict__ outb, float* __restrict__ outf, bf16* __restrict__ vt,
    int M, int N, int K) {
  __shared__ bf16 smem[4][128 * 64];          // [0..1]=A dbuf, [2..3]=B dbuf
  const int gx = gridDim.x;
  const int wg = xcd_remap(blockIdx.y * gx + blockIdx.x, gx * gridDim.y);
  const int bn = (wg % gx) * 128, bm = (wg / gx) * 128;
  const int t = threadIdx.x, lane = t & 63, wid = t >> 6;
  const int wr = wid >> 1, wc = wid & 1;
  const int g = lane >> 4, c = lane & 15;
  f32x4 acc[4][4];
#pragma unroll
  for (int i = 0; i < 4; ++i)
#pragma unroll
    for (int j = 0; j < 4; ++j) acc[i][j] = (f32x4){0.f, 0.f, 0.f, 0.f};
  const int nkt = K >> 6;

  auto stage = [&](int bb, int kt) {
#pragma unroll
    for (int j2 = 0; j2 < 4; ++j2) {
      int ch  = t + j2 * 256;                 // 0..1023 chunk (16B) index
      int row = ch >> 3;                      // 0..127
      int src = ((ch & 7) * 8) ^ ((row & 7) << 3);   // pre-swizzled source col
      gload_lds16(A  + (size_t)(bm + row) * K + kt * 64 + src, &smem[bb][ch * 8]);
      gload_lds16(Bt + (size_t)(bn + row) * K + kt * 64 + src, &smem[2 + bb][ch * 8]);
    }
  };

  stage(0, 0);
  const int swz = (c & 7) << 3;
  for (int kt = 0; kt < nkt; ++kt) {
    const int cb = kt & 1;
    if (kt + 1 < nkt) {
      stage(cb ^ 1, kt + 1);                  // prefetch flies under compute
      asm volatile("s_waitcnt vmcnt(8)" ::: "memory");   // wait current tile only
    } else {
      asm volatile("s_waitcnt vmcnt(0)" ::: "memory");
    }
    __builtin_amdgcn_s_barrier();
    __builtin_amdgcn_sched_barrier(0);
#pragma unroll
    for (int f = 0; f < 2; ++f) {
      bf16x8 aF[4], bF[4];
      const int e = (f * 32 + g * 8) ^ swz;
#pragma unroll
      for (int mt = 0; mt < 4; ++mt)
        aF[mt] = *(const bf16x8*)&smem[cb][(wr * 64 + mt * 16 + c) * 64 + e];
#pragma unroll
      for (int nt = 0; nt < 4; ++nt)
        bF[nt] = *(const bf16x8*)&smem[2 + cb][(wc * 64 + nt * 16 + c) * 64 + e];
      __builtin_amdgcn_s_setprio(1);
#pragma unroll
      for (int mt = 0; mt < 4; ++mt)
#pragma unroll
        for (int nt = 0; nt < 4; ++nt)
          acc[mt][nt] = __builtin_amdgcn_mfma_f32_16x16x32_bf16(
              aF[mt], bF[nt], acc[mt][nt], 0, 0, 0);
      __builtin_amdgcn_s_setprio(0);
    }
    __builtin_amdgcn_sched_barrier(0);
    __builtin_amdgcn_s_barrier();             // all done reading buf[cb]
  }
  // ---- epilogue: C/D layout col=lane&15, row=(lane>>4)*4+reg ----
  if (OUTMODE == 3 && bn >= 1536) {
    // V block: transpose C-tile via padded LDS, store coalesced to vt[b,h,d,s].
    bf16* ldsT = (bf16*)smem;                 // 128 x 136 bf16 = 34 KB (LDS free)
#pragma unroll
    for (int nt = 0; nt < 4; ++nt) {
      int lc = wc * 64 + nt * 16 + c;         // local col (= local d)
      float bv = bias[bn + lc];
#pragma unroll
      for (int mt = 0; mt < 4; ++mt) {
        int lr = wr * 64 + mt * 16 + g * 4;   // local row (= local s)
        bf16x4 pb;
#pragma unroll
        for (int r = 0; r < 4; ++r) pb[r] = (bf16)(acc[mt][nt][r] + bv);
        *(s16x4*)&ldsT[lc * 136 + lr] = __builtin_bit_cast(s16x4, pb);
      }
    }
    __syncthreads();
    const int vc0 = bn - 1536;                // global v-col base (0..640)
    const int bb_ = bm >> 11;                 // batch
    const int s0  = bm & 2047;                // s base
#pragma unroll
    for (int it = 0; it < 8; ++it) {
      int chunk = t + it * 256;               // 0..2047
      int d = chunk >> 4, sc = chunk & 15;
      bf16x8 v = *(const bf16x8*)&ldsT[d * 136 + sc * 8];
      int vcol = vc0 + d;
      size_t vrow = ((size_t)(bb_ * Hv + (vcol >> 6)) * 64 + (vcol & 63));
      *(bf16x8*)&vt[vrow * Sv + s0 + sc * 8] = v;
    }
    return;
  }
#pragma unroll
  for (int nt = 0; nt < 4; ++nt) {
    int col = bn + wc * 64 + nt * 16 + c;
    float bv = bias[col];
#pragma unroll
    for (int mt = 0; mt < 4; ++mt) {
      int row0 = bm + wr * 64 + mt * 16 + g * 4;
#pragma unroll
      for (int r = 0; r < 4; ++r) {
        float vv = acc[mt][nt][r] + bv;
        if (RELU) vv = fmaxf(vv, 0.f);
        size_t off = (size_t)(row0 + r) * N + col;
        if (RESID) { vv += hres[off]; hres[off] = vv; }
        if (OUTMODE == 1 || OUTMODE == 3) outb[off] = (bf16)vv;
        if (OUTMODE == 2) outf[off] = vv;
      }
    }
  }
}

// ---------------- 64x128 bf16 GEMM (skinny-N), dbuf, 48KB LDS -> 3 blocks/CU --------
template<bool RELU, bool RESID, int OUTMODE>
__global__ __launch_bounds__(256) void gemm_sk(
    const bf16* __restrict__ A, const bf16* __restrict__ Bt,
    const float* __restrict__ bias, float* __restrict__ hres,
    bf16* __restrict__ outb, float* __restrict__ outf, int M, int N, int K) {
  __shared__ bf16 sA[2][64 * 64];
  __shared__ bf16 sB[2][128 * 64];
  const int gx = gridDim.x;
  const int wg = xcd_remap(blockIdx.y * gx + blockIdx.x, gx * gridDim.y);
  const int bn = (wg % gx) * 128, bm = (wg / gx) * 64;
  const int t = threadIdx.x, lane = t & 63, wid = t >> 6;
  const int wr = wid >> 1, wc = wid & 1;      // 2M x 2N of 32x64 per wave
  const int g = lane >> 4, c = lane & 15;
  f32x4 acc[2][4];
#pragma unroll
  for (int i = 0; i < 2; ++i)
#pragma unroll
    for (int j = 0; j < 4; ++j) acc[i][j] = (f32x4){0.f, 0.f, 0.f, 0.f};
  const int nkt = K >> 6;

  auto stage = [&](int bb, int kt) {
#pragma unroll
    for (int j2 = 0; j2 < 2; ++j2) {          // A: 64x64 = 512 chunks
      int ch  = t + j2 * 256;
      int row = ch >> 3;                      // 0..63
      int src = ((ch & 7) * 8) ^ ((row & 7) << 3);
      gload_lds16(A + (size_t)(bm + row) * K + kt * 64 + src, &sA[bb][ch * 8]);
    }
#pragma unroll
    for (int j2 = 0; j2 < 4; ++j2) {          // B: 128x64 = 1024 chunks
      int ch  = t + j2 * 256;
      int row = ch >> 3;                      // 0..127
      int src = ((ch & 7) * 8) ^ ((row & 7) << 3);
      gload_lds16(Bt + (size_t)(bn + row) * K + kt * 64 + src, &sB[bb][ch * 8]);
    }
  };

  stage(0, 0);
  const int swz = (c & 7) << 3;
  for (int kt = 0; kt < nkt; ++kt) {
    const int cb = kt & 1;
    if (kt + 1 < nkt) {
      stage(cb ^ 1, kt + 1);
      asm volatile("s_waitcnt vmcnt(6)" ::: "memory");   // 6 loads/thread/stage
    } else {
      asm volatile("s_waitcnt vmcnt(0)" ::: "memory");
    }
    __builtin_amdgcn_s_barrier();
    __builtin_amdgcn_sched_barrier(0);
#pragma unroll
    for (int f = 0; f < 2; ++f) {
      bf16x8 aF[2], bF[4];
      const int e = (f * 32 + g * 8) ^ swz;
#pragma unroll
      for (int mt = 0; mt < 2; ++mt)
        aF[mt] = *(const bf16x8*)&sA[cb][(wr * 32 + mt * 16 + c) * 64 + e];
#pragma unroll
      for (int nt = 0; nt < 4; ++nt)
        bF[nt] = *(const bf16x8*)&sB[cb][(wc * 64 + nt * 16 + c) * 64 + e];
      __builtin_amdgcn_s_setprio(1);
#pragma unroll
      for (int mt = 0; mt < 2; ++mt)
#pragma unroll
        for (int nt = 0; nt < 4; ++nt)
          acc[mt][nt] = __builtin_amdgcn_mfma_f32_16x16x32_bf16(
              aF[mt], bF[nt], acc[mt][nt], 0, 0, 0);
      __builtin_amdgcn_s_setprio(0);
    }
    __builtin_amdgcn_sched_barrier(0);
    __builtin_amdgcn_s_barrier();
  }
  // epilogue
#pragma unroll
  for (int nt = 0; nt < 4; ++nt) {
    int col = bn + wc * 64 + nt * 16 + c;
    float bv = bias[col];
#pragma unroll
    for (int mt = 0; mt < 2; ++mt) {
      int row0 = bm + wr * 32 + mt * 16 + g * 4;
#pragma unroll
      for (int r = 0; r < 4; ++r) {
        float vv = acc[mt][nt][r] + bv;
        if (RELU) vv = fmaxf(vv, 0.f);
        size_t off = (size_t)(row0 + r) * N + col;
        if (RESID) { vv += hres[off]; hres[off] = vv; }
        if (OUTMODE == 1) outb[off] = (bf16)vv;
        if (OUTMODE == 2) outf[off] = vv;
      }
    }
  }
}

// ---------------- flash attention (swapped-QK^T, zero-shuffle PV, paired) ----------
// l-sum via ones-MFMA; max3-fused reduction.
__global__ __launch_bounds__(256) void attn_kernel(const bf16* __restrict__ qkv,
                                                   const bf16* __restrict__ vt,
                                                   bf16* __restrict__ o) {
  __shared__ bf16 sK[2][64 * 64], sVT[2][64 * 64];
  const int nwg = 16 * Bv * Hv;
  const int wgl = xcd_remap(blockIdx.y * 16 + blockIdx.x, nwg);
  const int i  = wgl % 16;                    // pair index 0..15
  const int bh = wgl / 16;
  const int qtA = i, qtB = 31 - i;
  const int b  = bh / Hv;
  const int h  = bh % Hv;
  const int t = threadIdx.x, lane = t & 63, wid = t >> 6;
  const int g = lane >> 4, c = lane & 15;
  const int QST = 2304;
  const bf16* qbase  = qkv + (size_t)b * Sv * QST + h * 64;
  const bf16* vtbase = vt + ((size_t)bh * 64) * Sv;
  const float CS = 0.18033688011112042f;      // (1/sqrt(64)) * log2(e)
  const float THR = 11.541560327111707f;      // 8 * log2(e) (defer-max)
  const int swz = (c & 7) << 3;
  const s16x4 onesf = {0x3F80, 0x3F80, 0x3F80, 0x3F80};   // bf16 1.0 x4

  bf16x8 qfA[2], qfB[2];
  {
    const bf16* qa = qbase + (size_t)(qtA * 64 + wid * 16 + c) * QST;
    qfA[0] = *(const bf16x8*)(qa + g * 8);
    qfA[1] = *(const bf16x8*)(qa + 32 + g * 8);
    const bf16* qb = qbase + (size_t)(qtB * 64 + wid * 16 + c) * QST;
    qfB[0] = *(const bf16x8*)(qb + g * 8);
    qfB[1] = *(const bf16x8*)(qb + 32 + g * 8);
  }
  f32x4 accA[4], accB[4];
  f32x4 accLA = {0.f, 0.f, 0.f, 0.f}, accLB = {0.f, 0.f, 0.f, 0.f};
  float mA = -INFINITY, mB = -INFINITY;
#pragma unroll
  for (int d0 = 0; d0 < 4; ++d0) {
    accA[d0] = (f32x4){0.f, 0.f, 0.f, 0.f};
    accB[d0] = (f32x4){0.f, 0.f, 0.f, 0.f};
  }
  const int qlA = qtA * 64 + wid * 16 + c;    // this lane's softmax query (A)
  const int qlB = qtB * 64 + wid * 16 + c;

  auto stage = [&](int bb, int kt) {
#pragma unroll
    for (int j2 = 0; j2 < 2; ++j2) {
      int ch  = t + j2 * 256;                 // 0..511
      int row = ch >> 3;                      // 0..63
      int src = ((ch & 7) * 8) ^ ((row & 7) << 3);
      gload_lds16(qbase + (size_t)(kt * 64 + row) * QST + 768 + src, &sK[bb][ch * 8]);
      gload_lds16(vtbase + (size_t)row * Sv + kt * 64 + src, &sVT[bb][ch * 8]);
    }
  };

  auto process = [&](int bb, const bf16x8* qf, f32x4* accO, f32x4& accL,
                     float& m_s, int ql, int kt, bool diag) {
    f32x4 accT[4];
#pragma unroll
    for (int nt = 0; nt < 4; ++nt) accT[nt] = (f32x4){0.f, 0.f, 0.f, 0.f};
    __builtin_amdgcn_s_setprio(1);
#pragma unroll
    for (int nt = 0; nt < 4; ++nt)
#pragma unroll
      for (int f = 0; f < 2; ++f) {
        bf16x8 kf = *(const bf16x8*)&sK[bb][(nt * 16 + c) * 64 + ((f * 32 + g * 8) ^ swz)];
        accT[nt] = __builtin_amdgcn_mfma_f32_16x16x32_bf16(kf, qf[f], accT[nt], 0, 0, 0);
      }
    __builtin_amdgcn_s_setprio(0);
    if (diag) {                               // wave-uniform branch; raw-score mask
#pragma unroll
      for (int nt = 0; nt < 4; ++nt)
#pragma unroll
        for (int r = 0; r < 4; ++r)
          if ((kt * 64 + nt * 16 + g * 4 + r) > ql) accT[nt][r] = -INFINITY;
    }
    // max3-fused reduction (clang folds fmaxf(fmaxf(a,b),c) -> v_max3_f32)
    float mnt[4];
#pragma unroll
    for (int nt = 0; nt < 4; ++nt)
      mnt[nt] = fmaxf(fmaxf(fmaxf(accT[nt][0], accT[nt][1]), accT[nt][2]),
                      accT[nt][3]);
    float mt = fmaxf(fmaxf(fmaxf(mnt[0], mnt[1]), mnt[2]), mnt[3]);
    mt *= CS;
    mt = fmaxf(mt, __shfl_xor(mt, 16, 64));
    mt = fmaxf(mt, __shfl_xor(mt, 32, 64));
    const bool skip = __all(mt <= m_s + THR);   // defer-max (wave-uniform)
    const float mn = skip ? m_s : fmaxf(m_s, mt);
    if (!skip) {
      float al = __builtin_amdgcn_exp2f(m_s - mn);
      m_s = mn;
#pragma unroll
      for (int r = 0; r < 4; ++r) {
        float alq = __shfl(al, g * 4 + r, 64); // al of query g*4+r (lanes 0..15)
        accL[r] *= alq;
#pragma unroll
        for (int d0 = 0; d0 < 4; ++d0) accO[d0][r] *= alq;
      }
    }
#pragma unroll
    for (int nt = 0; nt < 4; ++nt)
#pragma unroll
      for (int r = 0; r < 4; ++r)
        accT[nt][r] = __builtin_amdgcn_exp2f(fmaf(accT[nt][r], CS, -mn));
    // PV from registers: pa[nt] = A-frag (row=query c, k=g*4+e) of K=16 slice nt
    s16x4 pa[4];
#pragma unroll
    for (int nt = 0; nt < 4; ++nt) {
      bf16x4 pb;
#pragma unroll
      for (int r = 0; r < 4; ++r) pb[r] = (bf16)accT[nt][r];
      pa[nt] = __builtin_bit_cast(s16x4, pb);
    }
    __builtin_amdgcn_s_setprio(1);
#pragma unroll
    for (int nt = 0; nt < 4; ++nt)            // denominator: accL += P . ones
      accL = __builtin_amdgcn_mfma_f32_16x16x16bf16_1k(pa[nt], onesf, accL, 0, 0, 0);
#pragma unroll
    for (int d0 = 0; d0 < 4; ++d0) {
      const int drow = (d0 * 16 + c) * 64;
#pragma unroll
      for (int nt = 0; nt < 4; ++nt) {
        int chunk = (nt * 2 + (g >> 1)) ^ (c & 7);
        s16x4 vfr = *(const s16x4*)&sVT[bb][drow + chunk * 8 + (g & 1) * 4];
        accO[d0] = __builtin_amdgcn_mfma_f32_16x16x16bf16_1k(pa[nt], vfr, accO[d0], 0, 0, 0);
      }
    }
    __builtin_amdgcn_s_setprio(0);
  };

  stage(0, 0);
  int cur = 0;
  for (int kt = 0; kt <= qtB; ++kt) {
    __syncthreads();                          // publishes buf[cur] (vmcnt drain)
    if (kt < qtB) stage(cur ^ 1, kt + 1);     // prefetch flies under compute
    if (kt <= qtA) process(cur, qfA, accA, accLA, mA, qlA, kt, kt == qtA);
    process(cur, qfB, accB, accLB, mB, qlB, kt, kt == qtB);
    cur ^= 1;
  }

  // normalize + store; accO/accL row r = query g*4+r (no shuffles needed)
#pragma unroll
  for (int r = 0; r < 4; ++r) {
    float iA = 1.f / accLA[r];
    float iB = 1.f / accLB[r];
    size_t orA = (size_t)b * Sv + qtA * 64 + wid * 16 + g * 4 + r;
    size_t orB = (size_t)b * Sv + qtB * 64 + wid * 16 + g * 4 + r;
#pragma unroll
    for (int d0 = 0; d0 < 4; ++d0) {
      o[orA * Dv + h * 64 + d0 * 16 + c] = (bf16)(accA[d0][r] * iA);
      o[orB * Dv + h * 64 + d0 * 16 + c] = (bf16)(accB[d0][r] * iB);
    }
  }
}

// ---------------- host launch ----------------
extern "C" void kernel_launch(void* const* d_in, const int* in_sizes, int n_in,
                              void* d_out, int out_size, void* d_ws, size_t ws_size,
                              hipStream_t stream) {
  const int*   x     = (const int*)d_in[0];
  const float* emb   = (const float*)d_in[1];
  const float* qkv_w = (const float*)d_in[2];
  const float* qkv_b = (const float*)d_in[3];
  const float* out_w = (const float*)d_in[4];
  const float* out_b = (const float*)d_in[5];
  const float* ln1_s = (const float*)d_in[6];
  const float* ln1_b = (const float*)d_in[7];
  const float* w1    = (const float*)d_in[8];
  const float* b1    = (const float*)d_in[9];
  const float* w2    = (const float*)d_in[10];
  const float* b2    = (const float*)d_in[11];
  const float* ln2_s = (const float*)d_in[12];
  const float* ln2_b = (const float*)d_in[13];
  const float* lnf_s = (const float*)d_in[14];
  const float* lnf_b = (const float*)d_in[15];
  const float* head_w= (const float*)d_in[16];
  const float* head_b= (const float*)d_in[17];
  float* out = (float*)d_out;                 // reference output dtype = float32
  (void)in_sizes; (void)n_in; (void)out_size;

  char* ws = (char*)d_ws;
  size_t off = 0;
  auto alloc = [&](size_t bytes) -> char* {
    char* p = ws + off; off += (bytes + 255) & ~(size_t)255; return p;
  };
  float* hbuf  = (float*)alloc((size_t)Mv * Dv * 4);        // fp32 residual stream
  bf16*  xn    = (bf16*) alloc((size_t)Mv * Dv * 2);        // LN output
  bf16*  qkvff = (bf16*) alloc((size_t)Mv * Fv * 2);        // qkv (M*2304) / ff (M*3072)
  bf16*  vt    = (bf16*) alloc((size_t)Bv * Hv * 64 * Sv * 2); // V^T [b,h,d,s]
  bf16*  attn_o= (bf16*) alloc((size_t)Mv * Dv * 2);
  bf16*  qkvT  = (bf16*) alloc((size_t)Lv * 3 * Dv * Dv * 2); // all-layer transposed W
  bf16*  outT  = (bf16*) alloc((size_t)Lv * Dv * Dv * 2);
  bf16*  w1T   = (bf16*) alloc((size_t)Lv * Fv * Dv * 2);
  bf16*  w2T   = (bf16*) alloc((size_t)Lv * Fv * Dv * 2);
  bf16*  headT = (bf16*) alloc((size_t)Vv * Dv * 2);
  int*   i64f  = (int*)  alloc(256);

  fprintf(stderr, "[kernel_launch] ws_size=%zu needed=%zu out_size=%d\n",
          ws_size, off, out_size);
  if (off > ws_size) {
    fprintf(stderr, "[kernel_launch] WORKSPACE TOO SMALL - not launching\n");
    return;
  }

  detect_i64<<<1, 256, 0, stream>>>(x, i64f);
  transpose_cvt<<<dim3(36, 12, Lv), 256, 0, stream>>>(qkv_w, qkvT, Dv, 3 * Dv);
  transpose_cvt<<<dim3(12, 12, Lv), 256, 0, stream>>>(out_w, outT, Dv, Dv);
  transpose_cvt<<<dim3(48, 12, Lv), 256, 0, stream>>>(w1, w1T, Dv, Fv);
  transpose_cvt<<<dim3(12, 48, Lv), 256, 0, stream>>>(w2, w2T, Fv, Dv);
  transpose_cvt<<<dim3(8, 12, 1), 256, 0, stream>>>(head_w, headT, Dv, Vv);
  embed_kernel<<<Mv * (Dv / 2) / 256, 256, 0, stream>>>(x, emb, hbuf, i64f);

  for (int l = 0; l < Lv; ++l) {
    ln_kernel<<<Mv / 4, 256, 0, stream>>>(hbuf, ln1_s + l * Dv, ln1_b + l * Dv, xn);
    gemm_bt<false, false, 3><<<dim3(3 * Dv / 128, Mv / 128), 256, 0, stream>>>(
        xn, qkvT + (size_t)l * 3 * Dv * Dv, qkv_b + l * 3 * Dv, nullptr, qkvff,
        nullptr, vt, Mv, 3 * Dv, Dv);
    attn_kernel<<<dim3(16, Bv * Hv), 256, 0, stream>>>(qkvff, vt, attn_o);
    gemm_sk<false, true, 0><<<dim3(Dv / 128, Mv / 64), 256, 0, stream>>>(
        attn_o, outT + (size_t)l * Dv * Dv, out_b + l * Dv, hbuf, nullptr,
        nullptr, Mv, Dv, Dv);
    ln_kernel<<<Mv / 4, 256, 0, stream>>>(hbuf, ln2_s + l * Dv, ln2_b + l * Dv, xn);
    gemm_bt<true, false, 1><<<dim3(Fv / 128, Mv / 128), 256, 0, stream>>>(
        xn, w1T + (size_t)l * Fv * Dv, b1 + l * Fv, nullptr, qkvff, nullptr,
        nullptr, Mv, Fv, Dv);
    gemm_sk<false, true, 0><<<dim3(Dv / 128, Mv / 64), 256, 0, stream>>>(
        qkvff, w2T + (size_t)l * Fv * Dv, b2 + l * Dv, hbuf, nullptr, nullptr,
        Mv, Dv, Fv);
  }
  ln_kernel<<<Mv / 4, 256, 0, stream>>>(hbuf, lnf_s, lnf_b, xn);
  gemm_sk<false, false, 2><<<dim3(Vv / 128, Mv / 64), 256, 0, stream>>>(
      xn, headT, head_b, nullptr, nullptr, out, Mv, Vv, Dv);
}

// Round 19
// 1489.964 us; speedup vs baseline: 1.0490x; 1.0409x over previous
//
#include <hip/hip_runtime.h>
#include <math.h>
#include <stdio.h>

#define Bv 4
#define Sv 2048
#define Dv 768
#define Hv 12
#define Lv 6
#define Fv 3072
#define Vv 512
#define Mv (Bv*Sv)   // 8192 rows

typedef __bf16 bf16;
typedef __bf16 bf16x2 __attribute__((ext_vector_type(2)));
typedef __bf16 bf16x8 __attribute__((ext_vector_type(8)));
typedef __bf16 bf16x4 __attribute__((ext_vector_type(4)));
typedef short  s16x4  __attribute__((ext_vector_type(4)));
typedef float  f32x4  __attribute__((ext_vector_type(4)));

// global -> LDS async copy, 16B per lane. LDS dest is wave-uniform base + lane*16.
__device__ __forceinline__ void gload_lds16(const void* g, void* l) {
  __builtin_amdgcn_global_load_lds(
      (__attribute__((address_space(1))) void*)(void*)g,
      (__attribute__((address_space(3))) void*)l, 16, 0, 0);
}

// bijective XCD-aware remap of a linear workgroup id (m204 formula)
__device__ __forceinline__ int xcd_remap(int orig, int nwg) {
  int q = nwg >> 3, r = nwg & 7;
  int xcd = orig & 7, loc = orig >> 3;
  return (xcd < r ? xcd * (q + 1) : r * (q + 1) + (xcd - r) * q) + loc;
}

// ---------------- token dtype probe: int64 -> all odd 32-bit words zero ----------------
__global__ void detect_i64(const int* __restrict__ x, int* __restrict__ flag) {
  __shared__ int red[256];
  int acc = 0;
  for (int i = threadIdx.x; i < Mv / 2; i += 256) acc |= x[2 * i + 1];
  red[threadIdx.x] = acc;
  __syncthreads();
  for (int s = 128; s > 0; s >>= 1) {
    if (threadIdx.x < s) red[threadIdx.x] |= red[threadIdx.x + s];
    __syncthreads();
  }
  if (threadIdx.x == 0) *flag = (red[0] == 0) ? 1 : 0;
}

// ---------------- embedding + sinusoidal positional encoding (bf16 residual) --------
__global__ void embed_kernel(const int* __restrict__ x, const float* __restrict__ emb,
                             bf16* __restrict__ h, const int* __restrict__ i64flag) {
  int idx = blockIdx.x * 256 + threadIdx.x;       // over Mv * (Dv/2)
  int j  = idx % (Dv / 2);
  int bs = idx / (Dv / 2);
  int s  = bs % Sv;
  int tok = (*i64flag) ? x[2 * bs] : x[bs];
  float2 e = *(const float2*)(emb + (size_t)tok * Dv + 2 * j);
  float div = expf((float)(2 * j) * (-9.210340371976184f / (float)Dv)); // -ln(10000)/D
  float arg = (float)s * div;
  const float sq = 27.712812921102035f;           // sqrt(768)
  bf16x2 o;
  o[0] = (bf16)(e.x * sq + sinf(arg));
  o[1] = (bf16)(e.y * sq + cosf(arg));
  *(bf16x2*)(h + (size_t)bs * Dv + 2 * j) = o;
}

// ---------------- fp32 [K,N] -> bf16 [N,K] tiled transpose-convert (z = layer) --------
__global__ void transpose_cvt(const float* __restrict__ in, bf16* __restrict__ out,
                              int K, int N) {
  __shared__ float tile[64][65];
  in  += (size_t)blockIdx.z * K * N;
  out += (size_t)blockIdx.z * K * N;
  int n0 = blockIdx.x * 64, k0 = blockIdx.y * 64;
  int tx = threadIdx.x & 63, ty = threadIdx.x >> 6;
#pragma unroll
  for (int i = 0; i < 64; i += 4)
    tile[ty + i][tx] = in[(size_t)(k0 + ty + i) * N + n0 + tx];
  __syncthreads();
#pragma unroll
  for (int i = 0; i < 64; i += 4)
    out[(size_t)(n0 + ty + i) * K + k0 + tx] = (bf16)tile[tx][ty + i];
}

// ---------------- LayerNorm: bf16 in -> bf16 out, one wave per row ----------------
__global__ void ln_kernel(const bf16* __restrict__ hin, const float* __restrict__ sc,
                          const float* __restrict__ bi, bf16* __restrict__ out) {
  int row  = blockIdx.x * 4 + (threadIdx.x >> 6);
  int lane = threadIdx.x & 63;
  const bf16* p = hin + (size_t)row * Dv + lane * 12;
  bf16 v16[12];
  *(s16x4*)(v16)     = *(const s16x4*)(p);
  *(s16x4*)(v16 + 4) = *(const s16x4*)(p + 4);
  *(s16x4*)(v16 + 8) = *(const s16x4*)(p + 8);
  float v[12];
#pragma unroll
  for (int j = 0; j < 12; ++j) v[j] = (float)v16[j];
  float sum = 0.f, sq = 0.f;
#pragma unroll
  for (int j = 0; j < 12; ++j) { sum += v[j]; sq += v[j] * v[j]; }
#pragma unroll
  for (int m = 1; m < 64; m <<= 1) {
    sum += __shfl_xor(sum, m, 64);
    sq  += __shfl_xor(sq,  m, 64);
  }
  float mu  = sum * (1.f / 768.f);
  float var = sq * (1.f / 768.f) - mu * mu;
  float rs  = rsqrtf(var + 1e-5f);
  float s_[12], b_[12];
  const float* scp = sc + lane * 12;
  const float* bip = bi + lane * 12;
  *(float4*)(s_)     = *(const float4*)(scp);
  *(float4*)(s_ + 4) = *(const float4*)(scp + 4);
  *(float4*)(s_ + 8) = *(const float4*)(scp + 8);
  *(float4*)(b_)     = *(const float4*)(bip);
  *(float4*)(b_ + 4) = *(const float4*)(bip + 4);
  *(float4*)(b_ + 8) = *(const float4*)(bip + 8);
  union { bf16 h2[12]; uint2 q[3]; } ob;
#pragma unroll
  for (int j = 0; j < 12; ++j)
    ob.h2[j] = (bf16)((v[j] - mu) * rs * s_[j] + b_[j]);
  uint2* op = (uint2*)(out + (size_t)row * Dv + lane * 12);
  op[0] = ob.q[0]; op[1] = ob.q[1]; op[2] = ob.q[2];
}

// ---------------- 128x128 bf16 GEMM, counted-vmcnt double-buffered staging ----------
// OUTMODE: 0 = none (resid only), 1 = bf16 out, 2 = f32 out,
//          3 = QKV fused: bn<1536 -> bf16 out (Q,K); bn>=1536 -> V transposed
//              to vt[b,h,d,s] via padded-LDS transpose (coalesced 16B stores).
template<bool RELU, bool RESID, int OUTMODE>
__global__ __launch_bounds__(256) void gemm_bt(
    const bf16* __restrict__ A, const bf16* __restrict__ Bt,
    const float* __restrict__ bias, bf16* __restrict__ hres,
    bf16* __restrict__ outb, float* __restrict__ outf, bf16* __restrict__ vt,
    int M, int N, int K) {
  __shared__ bf16 smem[4][128 * 64];          // [0..1]=A dbuf, [2..3]=B dbuf
  const int gx = gridDim.x;
  const int wg = xcd_remap(blockIdx.y * gx + blockIdx.x, gx * gridDim.y);
  const int bn = (wg % gx) * 128, bm = (wg / gx) * 128;
  const int t = threadIdx.x, lane = t & 63, wid = t >> 6;
  const int wr = wid >> 1, wc = wid & 1;
  const int g = lane >> 4, c = lane & 15;
  f32x4 acc[4][4];
#pragma unroll
  for (int i = 0; i < 4; ++i)
#pragma unroll
    for (int j = 0; j < 4; ++j) acc[i][j] = (f32x4){0.f, 0.f, 0.f, 0.f};
  const int nkt = K >> 6;

  auto stage = [&](int bb, int kt) {
#pragma unroll
    for (int j2 = 0; j2 < 4; ++j2) {
      int ch  = t + j2 * 256;                 // 0..1023 chunk (16B) index
      int row = ch >> 3;                      // 0..127
      int src = ((ch & 7) * 8) ^ ((row & 7) << 3);   // pre-swizzled source col
      gload_lds16(A  + (size_t)(bm + row) * K + kt * 64 + src, &smem[bb][ch * 8]);
      gload_lds16(Bt + (size_t)(bn + row) * K + kt * 64 + src, &smem[2 + bb][ch * 8]);
    }
  };

  stage(0, 0);
  const int swz = (c & 7) << 3;
  for (int kt = 0; kt < nkt; ++kt) {
    const int cb = kt & 1;
    if (kt + 1 < nkt) {
      stage(cb ^ 1, kt + 1);                  // prefetch flies under compute
      asm volatile("s_waitcnt vmcnt(8)" ::: "memory");   // wait current tile only
    } else {
      asm volatile("s_waitcnt vmcnt(0)" ::: "memory");
    }
    __builtin_amdgcn_s_barrier();
    __builtin_amdgcn_sched_barrier(0);
#pragma unroll
    for (int f = 0; f < 2; ++f) {
      bf16x8 aF[4], bF[4];
      const int e = (f * 32 + g * 8) ^ swz;
#pragma unroll
      for (int mt = 0; mt < 4; ++mt)
        aF[mt] = *(const bf16x8*)&smem[cb][(wr * 64 + mt * 16 + c) * 64 + e];
#pragma unroll
      for (int nt = 0; nt < 4; ++nt)
        bF[nt] = *(const bf16x8*)&smem[2 + cb][(wc * 64 + nt * 16 + c) * 64 + e];
      __builtin_amdgcn_s_setprio(1);
#pragma unroll
      for (int mt = 0; mt < 4; ++mt)
#pragma unroll
        for (int nt = 0; nt < 4; ++nt)
          acc[mt][nt] = __builtin_amdgcn_mfma_f32_16x16x32_bf16(
              aF[mt], bF[nt], acc[mt][nt], 0, 0, 0);
      __builtin_amdgcn_s_setprio(0);
    }
    __builtin_amdgcn_sched_barrier(0);
    __builtin_amdgcn_s_barrier();             // all done reading buf[cb]
  }
  // ---- epilogue: C/D layout col=lane&15, row=(lane>>4)*4+reg ----
  if (OUTMODE == 3 && bn >= 1536) {
    // V block: transpose C-tile via padded LDS, store coalesced to vt[b,h,d,s].
    bf16* ldsT = (bf16*)smem;                 // 128 x 136 bf16 = 34 KB (LDS free)
#pragma unroll
    for (int nt = 0; nt < 4; ++nt) {
      int lc = wc * 64 + nt * 16 + c;         // local col (= local d)
      float bv = bias[bn + lc];
#pragma unroll
      for (int mt = 0; mt < 4; ++mt) {
        int lr = wr * 64 + mt * 16 + g * 4;   // local row (= local s)
        bf16x4 pb;
#pragma unroll
        for (int r = 0; r < 4; ++r) pb[r] = (bf16)(acc[mt][nt][r] + bv);
        *(s16x4*)&ldsT[lc * 136 + lr] = __builtin_bit_cast(s16x4, pb);
      }
    }
    __syncthreads();
    const int vc0 = bn - 1536;                // global v-col base (0..640)
    const int bb_ = bm >> 11;                 // batch
    const int s0  = bm & 2047;                // s base
#pragma unroll
    for (int it = 0; it < 8; ++it) {
      int chunk = t + it * 256;               // 0..2047
      int d = chunk >> 4, sc = chunk & 15;
      bf16x8 v = *(const bf16x8*)&ldsT[d * 136 + sc * 8];
      int vcol = vc0 + d;
      size_t vrow = ((size_t)(bb_ * Hv + (vcol >> 6)) * 64 + (vcol & 63));
      *(bf16x8*)&vt[vrow * Sv + s0 + sc * 8] = v;
    }
    return;
  }
#pragma unroll
  for (int nt = 0; nt < 4; ++nt) {
    int col = bn + wc * 64 + nt * 16 + c;
    float bv = bias[col];
#pragma unroll
    for (int mt = 0; mt < 4; ++mt) {
      int row0 = bm + wr * 64 + mt * 16 + g * 4;
#pragma unroll
      for (int r = 0; r < 4; ++r) {
        float vv = acc[mt][nt][r] + bv;
        if (RELU) vv = fmaxf(vv, 0.f);
        size_t off = (size_t)(row0 + r) * N + col;
        if (RESID) { vv += (float)hres[off]; hres[off] = (bf16)vv; }
        if (OUTMODE == 1 || OUTMODE == 3) outb[off] = (bf16)vv;
        if (OUTMODE == 2) outf[off] = vv;
      }
    }
  }
}

// ---------------- 64x128 bf16 GEMM (skinny-N), dbuf, 48KB LDS -> 3 blocks/CU --------
template<bool RELU, bool RESID, int OUTMODE>
__global__ __launch_bounds__(256) void gemm_sk(
    const bf16* __restrict__ A, const bf16* __restrict__ Bt,
    const float* __restrict__ bias, bf16* __restrict__ hres,
    bf16* __restrict__ outb, float* __restrict__ outf, int M, int N, int K) {
  __shared__ bf16 sA[2][64 * 64];
  __shared__ bf16 sB[2][128 * 64];
  const int gx = gridDim.x;
  const int wg = xcd_remap(blockIdx.y * gx + blockIdx.x, gx * gridDim.y);
  const int bn = (wg % gx) * 128, bm = (wg / gx) * 64;
  const int t = threadIdx.x, lane = t & 63, wid = t >> 6;
  const int wr = wid >> 1, wc = wid & 1;      // 2M x 2N of 32x64 per wave
  const int g = lane >> 4, c = lane & 15;
  f32x4 acc[2][4];
#pragma unroll
  for (int i = 0; i < 2; ++i)
#pragma unroll
    for (int j = 0; j < 4; ++j) acc[i][j] = (f32x4){0.f, 0.f, 0.f, 0.f};
  const int nkt = K >> 6;

  auto stage = [&](int bb, int kt) {
#pragma unroll
    for (int j2 = 0; j2 < 2; ++j2) {          // A: 64x64 = 512 chunks
      int ch  = t + j2 * 256;
      int row = ch >> 3;                      // 0..63
      int src = ((ch & 7) * 8) ^ ((row & 7) << 3);
      gload_lds16(A + (size_t)(bm + row) * K + kt * 64 + src, &sA[bb][ch * 8]);
    }
#pragma unroll
    for (int j2 = 0; j2 < 4; ++j2) {          // B: 128x64 = 1024 chunks
      int ch  = t + j2 * 256;
      int row = ch >> 3;                      // 0..127
      int src = ((ch & 7) * 8) ^ ((row & 7) << 3);
      gload_lds16(Bt + (size_t)(bn + row) * K + kt * 64 + src, &sB[bb][ch * 8]);
    }
  };

  stage(0, 0);
  const int swz = (c & 7) << 3;
  for (int kt = 0; kt < nkt; ++kt) {
    const int cb = kt & 1;
    if (kt + 1 < nkt) {
      stage(cb ^ 1, kt + 1);
      asm volatile("s_waitcnt vmcnt(6)" ::: "memory");   // 6 loads/thread/stage
    } else {
      asm volatile("s_waitcnt vmcnt(0)" ::: "memory");
    }
    __builtin_amdgcn_s_barrier();
    __builtin_amdgcn_sched_barrier(0);
#pragma unroll
    for (int f = 0; f < 2; ++f) {
      bf16x8 aF[2], bF[4];
      const int e = (f * 32 + g * 8) ^ swz;
#pragma unroll
      for (int mt = 0; mt < 2; ++mt)
        aF[mt] = *(const bf16x8*)&sA[cb][(wr * 32 + mt * 16 + c) * 64 + e];
#pragma unroll
      for (int nt = 0; nt < 4; ++nt)
        bF[nt] = *(const bf16x8*)&sB[cb][(wc * 64 + nt * 16 + c) * 64 + e];
      __builtin_amdgcn_s_setprio(1);
#pragma unroll
      for (int mt = 0; mt < 2; ++mt)
#pragma unroll
        for (int nt = 0; nt < 4; ++nt)
          acc[mt][nt] = __builtin_amdgcn_mfma_f32_16x16x32_bf16(
              aF[mt], bF[nt], acc[mt][nt], 0, 0, 0);
      __builtin_amdgcn_s_setprio(0);
    }
    __builtin_amdgcn_sched_barrier(0);
    __builtin_amdgcn_s_barrier();
  }
  // epilogue
#pragma unroll
  for (int nt = 0; nt < 4; ++nt) {
    int col = bn + wc * 64 + nt * 16 + c;
    float bv = bias[col];
#pragma unroll
    for (int mt = 0; mt < 2; ++mt) {
      int row0 = bm + wr * 32 + mt * 16 + g * 4;
#pragma unroll
      for (int r = 0; r < 4; ++r) {
        float vv = acc[mt][nt][r] + bv;
        if (RELU) vv = fmaxf(vv, 0.f);
        size_t off = (size_t)(row0 + r) * N + col;
        if (RESID) { vv += (float)hres[off]; hres[off] = (bf16)vv; }
        if (OUTMODE == 1) outb[off] = (bf16)vv;
        if (OUTMODE == 2) outf[off] = vv;
      }
    }
  }
}

// ---------------- flash attention (swapped-QK^T, zero-shuffle PV, paired) ----------
// l-sum via ones-MFMA; max3-fused reduction.
__global__ __launch_bounds__(256) void attn_kernel(const bf16* __restrict__ qkv,
                                                   const bf16* __restrict__ vt,
                                                   bf16* __restrict__ o) {
  __shared__ bf16 sK[2][64 * 64], sVT[2][64 * 64];
  const int nwg = 16 * Bv * Hv;
  const int wgl = xcd_remap(blockIdx.y * 16 + blockIdx.x, nwg);
  const int i  = wgl % 16;                    // pair index 0..15
  const int bh = wgl / 16;
  const int qtA = i, qtB = 31 - i;
  const int b  = bh / Hv;
  const int h  = bh % Hv;
  const int t = threadIdx.x, lane = t & 63, wid = t >> 6;
  const int g = lane >> 4, c = lane & 15;
  const int QST = 2304;
  const bf16* qbase  = qkv + (size_t)b * Sv * QST + h * 64;
  const bf16* vtbase = vt + ((size_t)bh * 64) * Sv;
  const float CS = 0.18033688011112042f;      // (1/sqrt(64)) * log2(e)
  const float THR = 11.541560327111707f;      // 8 * log2(e) (defer-max)
  const int swz = (c & 7) << 3;
  const s16x4 onesf = {0x3F80, 0x3F80, 0x3F80, 0x3F80};   // bf16 1.0 x4

  bf16x8 qfA[2], qfB[2];
  {
    const bf16* qa = qbase + (size_t)(qtA * 64 + wid * 16 + c) * QST;
    qfA[0] = *(const bf16x8*)(qa + g * 8);
    qfA[1] = *(const bf16x8*)(qa + 32 + g * 8);
    const bf16* qb = qbase + (size_t)(qtB * 64 + wid * 16 + c) * QST;
    qfB[0] = *(const bf16x8*)(qb + g * 8);
    qfB[1] = *(const bf16x8*)(qb + 32 + g * 8);
  }
  f32x4 accA[4], accB[4];
  f32x4 accLA = {0.f, 0.f, 0.f, 0.f}, accLB = {0.f, 0.f, 0.f, 0.f};
  float mA = -INFINITY, mB = -INFINITY;
#pragma unroll
  for (int d0 = 0; d0 < 4; ++d0) {
    accA[d0] = (f32x4){0.f, 0.f, 0.f, 0.f};
    accB[d0] = (f32x4){0.f, 0.f, 0.f, 0.f};
  }
  const int qlA = qtA * 64 + wid * 16 + c;    // this lane's softmax query (A)
  const int qlB = qtB * 64 + wid * 16 + c;

  auto stage = [&](int bb, int kt) {
#pragma unroll
    for (int j2 = 0; j2 < 2; ++j2) {
      int ch  = t + j2 * 256;                 // 0..511
      int row = ch >> 3;                      // 0..63
      int src = ((ch & 7) * 8) ^ ((row & 7) << 3);
      gload_lds16(qbase + (size_t)(kt * 64 + row) * QST + 768 + src, &sK[bb][ch * 8]);
      gload_lds16(vtbase + (size_t)row * Sv + kt * 64 + src, &sVT[bb][ch * 8]);
    }
  };

  auto process = [&](int bb, const bf16x8* qf, f32x4* accO, f32x4& accL,
                     float& m_s, int ql, int kt, bool diag) {
    f32x4 accT[4];
#pragma unroll
    for (int nt = 0; nt < 4; ++nt) accT[nt] = (f32x4){0.f, 0.f, 0.f, 0.f};
    __builtin_amdgcn_s_setprio(1);
#pragma unroll
    for (int nt = 0; nt < 4; ++nt)
#pragma unroll
      for (int f = 0; f < 2; ++f) {
        bf16x8 kf = *(const bf16x8*)&sK[bb][(nt * 16 + c) * 64 + ((f * 32 + g * 8) ^ swz)];
        accT[nt] = __builtin_amdgcn_mfma_f32_16x16x32_bf16(kf, qf[f], accT[nt], 0, 0, 0);
      }
    __builtin_amdgcn_s_setprio(0);
    if (diag) {                               // wave-uniform branch; raw-score mask
#pragma unroll
      for (int nt = 0; nt < 4; ++nt)
#pragma unroll
        for (int r = 0; r < 4; ++r)
          if ((kt * 64 + nt * 16 + g * 4 + r) > ql) accT[nt][r] = -INFINITY;
    }
    // max3-fused reduction (clang folds fmaxf(fmaxf(a,b),c) -> v_max3_f32)
    float mnt[4];
#pragma unroll
    for (int nt = 0; nt < 4; ++nt)
      mnt[nt] = fmaxf(fmaxf(fmaxf(accT[nt][0], accT[nt][1]), accT[nt][2]),
                      accT[nt][3]);
    float mt = fmaxf(fmaxf(fmaxf(mnt[0], mnt[1]), mnt[2]), mnt[3]);
    mt *= CS;
    mt = fmaxf(mt, __shfl_xor(mt, 16, 64));
    mt = fmaxf(mt, __shfl_xor(mt, 32, 64));
    const bool skip = __all(mt <= m_s + THR);   // defer-max (wave-uniform)
    const float mn = skip ? m_s : fmaxf(m_s, mt);
    if (!skip) {
      float al = __builtin_amdgcn_exp2f(m_s - mn);
      m_s = mn;
#pragma unroll
      for (int r = 0; r < 4; ++r) {
        float alq = __shfl(al, g * 4 + r, 64); // al of query g*4+r (lanes 0..15)
        accL[r] *= alq;
#pragma unroll
        for (int d0 = 0; d0 < 4; ++d0) accO[d0][r] *= alq;
      }
    }
#pragma unroll
    for (int nt = 0; nt < 4; ++nt)
#pragma unroll
      for (int r = 0; r < 4; ++r)
        accT[nt][r] = __builtin_amdgcn_exp2f(fmaf(accT[nt][r], CS, -mn));
    // PV from registers: pa[nt] = A-frag (row=query c, k=g*4+e) of K=16 slice nt
    s16x4 pa[4];
#pragma unroll
    for (int nt = 0; nt < 4; ++nt) {
      bf16x4 pb;
#pragma unroll
      for (int r = 0; r < 4; ++r) pb[r] = (bf16)accT[nt][r];
      pa[nt] = __builtin_bit_cast(s16x4, pb);
    }
    __builtin_amdgcn_s_setprio(1);
#pragma unroll
    for (int nt = 0; nt < 4; ++nt)            // denominator: accL += P . ones
      accL = __builtin_amdgcn_mfma_f32_16x16x16bf16_1k(pa[nt], onesf, accL, 0, 0, 0);
#pragma unroll
    for (int d0 = 0; d0 < 4; ++d0) {
      const int drow = (d0 * 16 + c) * 64;
#pragma unroll
      for (int nt = 0; nt < 4; ++nt) {
        int chunk = (nt * 2 + (g >> 1)) ^ (c & 7);
        s16x4 vfr = *(const s16x4*)&sVT[bb][drow + chunk * 8 + (g & 1) * 4];
        accO[d0] = __builtin_amdgcn_mfma_f32_16x16x16bf16_1k(pa[nt], vfr, accO[d0], 0, 0, 0);
      }
    }
    __builtin_amdgcn_s_setprio(0);
  };

  stage(0, 0);
  int cur = 0;
  for (int kt = 0; kt <= qtB; ++kt) {
    __syncthreads();                          // publishes buf[cur] (vmcnt drain)
    if (kt < qtB) stage(cur ^ 1, kt + 1);     // prefetch flies under compute
    if (kt <= qtA) process(cur, qfA, accA, accLA, mA, qlA, kt, kt == qtA);
    process(cur, qfB, accB, accLB, mB, qlB, kt, kt == qtB);
    cur ^= 1;
  }

  // normalize + store; accO/accL row r = query g*4+r (no shuffles needed)
#pragma unroll
  for (int r = 0; r < 4; ++r) {
    float iA = 1.f / accLA[r];
    float iB = 1.f / accLB[r];
    size_t orA = (size_t)b * Sv + qtA * 64 + wid * 16 + g * 4 + r;
    size_t orB = (size_t)b * Sv + qtB * 64 + wid * 16 + g * 4 + r;
#pragma unroll
    for (int d0 = 0; d0 < 4; ++d0) {
      o[orA * Dv + h * 64 + d0 * 16 + c] = (bf16)(accA[d0][r] * iA);
      o[orB * Dv + h * 64 + d0 * 16 + c] = (bf16)(accB[d0][r] * iB);
    }
  }
}

// ---------------- host launch ----------------
extern "C" void kernel_launch(void* const* d_in, const int* in_sizes, int n_in,
                              void* d_out, int out_size, void* d_ws, size_t ws_size,
                              hipStream_t stream) {
  const int*   x     = (const int*)d_in[0];
  const float* emb   = (const float*)d_in[1];
  const float* qkv_w = (const float*)d_in[2];
  const float* qkv_b = (const float*)d_in[3];
  const float* out_w = (const float*)d_in[4];
  const float* out_b = (const float*)d_in[5];
  const float* ln1_s = (const float*)d_in[6];
  const float* ln1_b = (const float*)d_in[7];
  const float* w1    = (const float*)d_in[8];
  const float* b1    = (const float*)d_in[9];
  const float* w2    = (const float*)d_in[10];
  const float* b2    = (const float*)d_in[11];
  const float* ln2_s = (const float*)d_in[12];
  const float* ln2_b = (const float*)d_in[13];
  const float* lnf_s = (const float*)d_in[14];
  const float* lnf_b = (const float*)d_in[15];
  const float* head_w= (const float*)d_in[16];
  const float* head_b= (const float*)d_in[17];
  float* out = (float*)d_out;                 // reference output dtype = float32
  (void)in_sizes; (void)n_in; (void)out_size;

  char* ws = (char*)d_ws;
  size_t off = 0;
  auto alloc = [&](size_t bytes) -> char* {
    char* p = ws + off; off += (bytes + 255) & ~(size_t)255; return p;
  };
  bf16*  hbuf  = (bf16*) alloc((size_t)Mv * Dv * 2);        // bf16 residual stream
  bf16*  xn    = (bf16*) alloc((size_t)Mv * Dv * 2);        // LN output
  bf16*  qkvff = (bf16*) alloc((size_t)Mv * Fv * 2);        // qkv (M*2304) / ff (M*3072)
  bf16*  vt    = (bf16*) alloc((size_t)Bv * Hv * 64 * Sv * 2); // V^T [b,h,d,s]
  bf16*  attn_o= (bf16*) alloc((size_t)Mv * Dv * 2);
  bf16*  qkvT  = (bf16*) alloc((size_t)Lv * 3 * Dv * Dv * 2); // all-layer transposed W
  bf16*  outT  = (bf16*) alloc((size_t)Lv * Dv * Dv * 2);
  bf16*  w1T   = (bf16*) alloc((size_t)Lv * Fv * Dv * 2);
  bf16*  w2T   = (bf16*) alloc((size_t)Lv * Fv * Dv * 2);
  bf16*  headT = (bf16*) alloc((size_t)Vv * Dv * 2);
  int*   i64f  = (int*)  alloc(256);

  fprintf(stderr, "[kernel_launch] ws_size=%zu needed=%zu out_size=%d\n",
          ws_size, off, out_size);
  if (off > ws_size) {
    fprintf(stderr, "[kernel_launch] WORKSPACE TOO SMALL - not launching\n");
    return;
  }

  detect_i64<<<1, 256, 0, stream>>>(x, i64f);
  transpose_cvt<<<dim3(36, 12, Lv), 256, 0, stream>>>(qkv_w, qkvT, Dv, 3 * Dv);
  transpose_cvt<<<dim3(12, 12, Lv), 256, 0, stream>>>(out_w, outT, Dv, Dv);
  transpose_cvt<<<dim3(48, 12, Lv), 256, 0, stream>>>(w1, w1T, Dv, Fv);
  transpose_cvt<<<dim3(12, 48, Lv), 256, 0, stream>>>(w2, w2T, Fv, Dv);
  transpose_cvt<<<dim3(8, 12, 1), 256, 0, stream>>>(head_w, headT, Dv, Vv);
  embed_kernel<<<Mv * (Dv / 2) / 256, 256, 0, stream>>>(x, emb, hbuf, i64f);

  for (int l = 0; l < Lv; ++l) {
    ln_kernel<<<Mv / 4, 256, 0, stream>>>(hbuf, ln1_s + l * Dv, ln1_b + l * Dv, xn);
    gemm_bt<false, false, 3><<<dim3(3 * Dv / 128, Mv / 128), 256, 0, stream>>>(
        xn, qkvT + (size_t)l * 3 * Dv * Dv, qkv_b + l * 3 * Dv, nullptr, qkvff,
        nullptr, vt, Mv, 3 * Dv, Dv);
    attn_kernel<<<dim3(16, Bv * Hv), 256, 0, stream>>>(qkvff, vt, attn_o);
    gemm_sk<false, true, 0><<<dim3(Dv / 128, Mv / 64), 256, 0, stream>>>(
        attn_o, outT + (size_t)l * Dv * Dv, out_b + l * Dv, hbuf, nullptr,
        nullptr, Mv, Dv, Dv);
    ln_kernel<<<Mv / 4, 256, 0, stream>>>(hbuf, ln2_s + l * Dv, ln2_b + l * Dv, xn);
    gemm_bt<true, false, 1><<<dim3(Fv / 128, Mv / 128), 256, 0, stream>>>(
        xn, w1T + (size_t)l * Fv * Dv, b1 + l * Fv, nullptr, qkvff, nullptr,
        nullptr, Mv, Fv, Dv);
    gemm_sk<false, true, 0><<<dim3(Dv / 128, Mv / 64), 256, 0, stream>>>(
        qkvff, w2T + (size_t)l * Fv * Dv, b2 + l * Dv, hbuf, nullptr, nullptr,
        Mv, Dv, Fv);
  }
  ln_kernel<<<Mv / 4, 256, 0, stream>>>(hbuf, lnf_s, lnf_b, xn);
  gemm_sk<false, false, 2><<<dim3(Vv / 128, Mv / 64), 256, 0, stream>>>(
      xn, headT, head_b, nullptr, nullptr, out, Mv, Vv, Dv);
}